// Round 5
// baseline (455.888 us; speedup 1.0000x reference)
//
#include <hip/hip_runtime.h>
#include <math.h>

// LocalSTD: out = sqrt( G*x^2 - (G*x)^2 + 1e-6 ), G = 11x11 Gaussian (sigma=1),
// separable. x: [16,64,256,256] fp32 = 1024 images of 256x256.
//
// R8 = R7 with the shuffle halo exchange moved from the DS pipe to the VALU
// pipe via DPP wave shifts. R7 (~151us) spent ~1856 cyc/CU-round on 20
// ds_bpermute per row-step (the largest per-round pipe consumer, ahead of
// HBM's ~1560) and serialized DS latency (lgkmcnt) inside each row's
// dependency chain. DPP wave_shr:1 / wave_shl:1 (gfx9-lineage, kept on CDNA)
// do lane+-1 shifts on the VALU at 2 cyc each with zero-fill at the wave edge
// (update_dpp old=0) -- which IS the image border zero-pad, so the boundary
// mask multiplies are deleted too. DS usage drops to zero; VALU gains ~24
// cheap ops/step. Ring, prefetch-by-2, and __launch_bounds__(256,4) are
// unchanged (R4/R6: exceeding the 128-VGPR cap spills 3-5x; don't).
//
// Wave = 64 lanes x 4 cols = full 256-col row. Vertical 11-tap from an 11-row
// float4 register ring. Horizontal 11-tap halo via 12 DPP shifts per stream.

#define W        256
#define IMG_PIX  (W * W)
#define BANDH    32          // output rows per wave; block = 4 waves = 128 rows

// normalized 1D Gaussian sigma=1 (2D kernel = outer product, sums factorize)
#define GW0 1.4867195e-06f   // |d|=5
#define GW1 1.3383023e-04f   // |d|=4
#define GW2 4.4318485e-03f   // |d|=3
#define GW3 5.3990965e-02f   // |d|=2
#define GW4 2.4197072e-01f   // |d|=1
#define GW5 3.9894228e-01f   // center

typedef float f4 __attribute__((ext_vector_type(4)));

__device__ __forceinline__ f4 vfma(float g, f4 a, f4 c) {
    f4 gv = {g, g, g, g};
    return __builtin_elementwise_fma(gv, a, c);   // -> v_pk_fma_f32 pairs
}

__device__ __forceinline__ f4 load_row(const float* __restrict__ xi, int gr, int c) {
    if ((unsigned)gr < (unsigned)W)
        return *(const f4*)(xi + (size_t)gr * W + c);
    return (f4){0.f, 0.f, 0.f, 0.f};
}

// DPP wave shifts (VALU pipe, no DS). Semantics per the GCN scan idiom
// (v_add_f32 ... row_shr:1 == lane i += lane i-1):
//   WAVE_SHR1 (0x138): lane i <- lane i-1, lane 0 invalid  == __shfl_up(v,1)
//   WAVE_SHL1 (0x130): lane i <- lane i+1, lane 63 invalid == __shfl_down(v,1)
// update_dpp with old=0: invalid lanes read 0 == image-border zero padding.
__device__ __forceinline__ float dpp_up1(float v) {   // lane i <- i-1, lane0 <- 0
    return __int_as_float(__builtin_amdgcn_update_dpp(
        0, __float_as_int(v), 0x138, 0xf, 0xf, false));
}
__device__ __forceinline__ float dpp_dn1(float v) {   // lane i <- i+1, lane63 <- 0
    return __int_as_float(__builtin_amdgcn_update_dpp(
        0, __float_as_int(v), 0x130, 0xf, 0xf, false));
}
__device__ __forceinline__ f4 dpp_up1_f4(f4 v) {
    f4 r;
    r.x = dpp_up1(v.x);
    r.y = dpp_up1(v.y);
    r.z = dpp_up1(v.z);
    r.w = dpp_up1(v.w);
    return r;
}
__device__ __forceinline__ f4 dpp_dn1_f4(f4 v) {
    f4 r;
    r.x = dpp_dn1(v.x);
    r.y = dpp_dn1(v.y);
    r.z = dpp_dn1(v.z);
    r.w = dpp_dn1(v.w);
    return r;
}

// Horizontal 11-tap for this lane's 4 cols of one stream. v = own float4
// (cols c..c+3). Halo via DPP wave shifts; wave edges == image edges, and the
// DPP zero-fill provides the zero padding directly (no masks).
__device__ __forceinline__ void hpass(f4 v, float h[4]) {
    f4 L = dpp_up1_f4(v);                    // lane i-1: cols c-4..c-1 (lane0: 0)
    float eL = dpp_up1(dpp_up1(v.w));        // lane i-2 col c-5 (lanes 0,1: 0)
    f4 R = dpp_dn1_f4(v);                    // lane i+1: cols c+4..c+7 (lane63: 0)
    float eR = dpp_dn1(dpp_dn1(v.x));        // lane i+2 col c+8 (lanes 62,63: 0)
    float F[14] = { eL,  L.x, L.y, L.z, L.w,
                    v.x, v.y, v.z, v.w,
                    R.x, R.y, R.z, R.w,  eR };   // F[k] = col c-5+k
    #pragma unroll
    for (int j = 0; j < 4; ++j) {
        float s = GW5 * F[j + 5];
        s = fmaf(GW4, F[j + 4] + F[j + 6],  s);
        s = fmaf(GW3, F[j + 3] + F[j + 7],  s);
        s = fmaf(GW2, F[j + 2] + F[j + 8],  s);
        s = fmaf(GW1, F[j + 1] + F[j + 9],  s);
        s = fmaf(GW0, F[j + 0] + F[j + 10], s);
        h[j] = s;
    }
}

// Ring slot of input row q is (q - r0 + 5) mod 11. Invariant at entry of step K
// (output row grow, (grow-r0)%11 == K): ring holds rows grow-6..grow+4;
// pf0 = row grow+5 (issued 2 steps ago, arrived), pf1 = row grow+6 (in
// flight). Step: insert pf0 (slot (K+10)%11, evicting dead row grow-6), issue
// prefetch of row grow+7, v-pass (packed fp32, squares recomputed -- saves 44
// VGPRs over a squares ring), h-pass, store, rotate prefetch regs.
template<int K>
__device__ __forceinline__ void row_step(const float* __restrict__ xi,
                                         float* __restrict__ oi,
                                         f4 (&xw)[11], f4& pf0, f4& pf1,
                                         int c, int grow) {
    constexpr int SN = (K + 10) % 11;
    xw[SN] = pf0;                                  // ring: rows grow-5..grow+5
    f4 pn = load_row(xi, grow + 7, c);             // arrives at step K+2

    // vertical 11-tap (symmetric pairs) on packed fp32
    constexpr int SC = (K + 5) % 11;
    f4 xc = xw[SC];
    f4 v1 = xc * GW5;
    f4 v2 = (xc * xc) * GW5;
    #define VPAIR(D, G) { constexpr int A_ = (K + 5 - (D)) % 11;                 \
                          constexpr int B_ = (K + 5 + (D)) % 11;                 \
                          f4 xa_ = xw[A_], xb_ = xw[B_];                         \
                          v1 = vfma(G, xa_ + xb_, v1);                           \
                          f4 sq_ = __builtin_elementwise_fma(xb_, xb_, xa_*xa_); \
                          v2 = vfma(G, sq_, v2); }
    VPAIR(1, GW4) VPAIR(2, GW3) VPAIR(3, GW2) VPAIR(4, GW1) VPAIR(5, GW0)
    #undef VPAIR

    // horizontal passes kept sequential (stream 1 then stream 2) to bound
    // live-range pressure.
    float h1[4], h2[4];
    hpass(v1, h1);
    hpass(v2, h2);

    f4 o;
    o.x = sqrtf(fmaf(-h1[0], h1[0], h2[0]) + 1e-6f);
    o.y = sqrtf(fmaf(-h1[1], h1[1], h2[1]) + 1e-6f);
    o.z = sqrtf(fmaf(-h1[2], h1[2], h2[2]) + 1e-6f);
    o.w = sqrtf(fmaf(-h1[3], h1[3], h2[3]) + 1e-6f);
    *(f4*)(oi + (size_t)grow * W + c) = o;

    pf0 = pf1;                                     // rotate prefetch pipeline
    pf1 = pn;
}

__global__ __launch_bounds__(256, 4) void
local_std_kernel(const float* __restrict__ x, float* __restrict__ out) {
    const int t    = threadIdx.x;
    const int wv   = t >> 6;
    const int lane = t & 63;
    const int bid  = blockIdx.x;
    const int img  = bid >> 1;                  // 2 blocks per image
    const int half = bid & 1;
    const float* xi = x   + (size_t)img * IMG_PIX;
    float*       oi = out + (size_t)img * IMG_PIX;

    const int c  = lane << 2;                   // this lane's 4 columns
    const int r0 = half * (W / 2) + wv * BANDH; // band start (wave-private)

    // warm-up: rows r0-5..r0+4 into slots 0..9; slot 10 is filled at step 0.
    f4 xw[11];
    #pragma unroll
    for (int i = 0; i < 10; ++i)
        xw[i] = load_row(xi, r0 - 5 + i, c);
    xw[10] = (f4){0.f, 0.f, 0.f, 0.f};
    f4 pf0 = load_row(xi, r0 + 5, c);           // for step 0 insert
    f4 pf1 = load_row(xi, r0 + 6, c);           // for step 1 insert

    // sweep 32 output rows; unroll-by-11 keeps ring/template indices static.
    // Outer loop kept rolled (uniform branches) to bound I-cache footprint.
    #pragma unroll 1
    for (int ii = 0; ii < 3; ++ii) {
        const int base = ii * 11;
        #define STEP(k) if (base + (k) < BANDH) \
            row_step<(k)>(xi, oi, xw, pf0, pf1, c, r0 + base + (k));
        STEP(0) STEP(1) STEP(2) STEP(3) STEP(4) STEP(5)
        STEP(6) STEP(7) STEP(8) STEP(9) STEP(10)
        #undef STEP
    }
}

extern "C" void kernel_launch(void* const* d_in, const int* in_sizes, int n_in,
                              void* d_out, int out_size, void* d_ws, size_t ws_size,
                              hipStream_t stream) {
    const float* x  = (const float*)d_in[0];
    float* out      = (float*)d_out;
    const int n_img = in_sizes[0] / IMG_PIX;    // 16*64 = 1024
    local_std_kernel<<<dim3(n_img * 2), 256, 0, stream>>>(x, out);
}